// Round 17
// baseline (313.976 us; speedup 1.0000x reference)
//
#include <hip/hip_runtime.h>
#include <hip/hip_bf16.h>

// GRU-D cell: B=16384, I=128, D=16 -- fully-staged streams + lane-local MFMA
// + per-block b-tile loop with async double-buffered staging (R17).
// Each block owns a 16-i range and loops over 8 b-tiles (tile k = y + k*128:
// device-wide marching slab preserved). Mechanisms vs R16:
//  (1) U/W/V/b gathers for the block's i-range become L1/L2-warm after
//      tile 0 (were cold per block = once per 16 rows).
//  (2) T14 async-stage: tile k+1's h/gamma loads issue into named registers
//      right after the top barrier, fly under the ~1400-cycle phase-2
//      compute, and are written to the alternate LDS buffer at the end --
//      steady-state phase-1 HBM stall eliminated.
// LDS 2 x 16.6 KB = 33 KB -> 4 blocks/CU (occupancy non-binding per R15).

typedef float  f32x4_t  __attribute__((ext_vector_type(4)));
typedef short  bf16x8_t __attribute__((ext_vector_type(8)));

constexpr int I_TOT = 128;
constexpr int ROWL  = 2048;   // floats per batch row (I*D)
constexpr int SW    = 260;    // LDS row stride in words (256 + 4 pad)
constexpr int NTK   = 8;      // b-tiles per block
constexpr int YB    = 128;    // grid.y

__device__ __forceinline__ unsigned short bf16c(float x) {
    union { __hip_bfloat16 b; unsigned short u; } cv;
    cv.b = __float2bfloat16(x);
    return cv.u;
}
__device__ __forceinline__ float bf16_to_f(unsigned short b) {
    union { float f; unsigned u; } c; c.u = ((unsigned)b) << 16;
    return c.f;
}
__device__ __forceinline__ float fast_sigmoid(float x) {
    float e = __expf(-x);
    return __builtin_amdgcn_rcpf(1.0f + e);
}
__device__ __forceinline__ float fast_tanh(float x) {
    x = fminf(fmaxf(x, -10.0f), 10.0f);
    float e = __expf(-2.0f * x);
    return (1.0f - e) * __builtin_amdgcn_rcpf(1.0f + e);
}

// compensated A fragment: [hi(a0..a3) | lo(a0..a3)]
__device__ __forceinline__ bf16x8_t build_a(float a0, float a1, float a2, float a3) {
    unsigned short h0 = bf16c(a0), h1 = bf16c(a1),
                   h2 = bf16c(a2), h3 = bf16c(a3);
    unsigned short l0 = bf16c(a0 - bf16_to_f(h0));
    unsigned short l1 = bf16c(a1 - bf16_to_f(h1));
    unsigned short l2 = bf16c(a2 - bf16_to_f(h2));
    unsigned short l3 = bf16c(a3 - bf16_to_f(h3));
    bf16x8_t A;
    A[0] = (short)h0; A[1] = (short)h1; A[2] = (short)h2; A[3] = (short)h3;
    A[4] = (short)l0; A[5] = (short)l1; A[6] = (short)l2; A[7] = (short)l3;
    return A;
}

// U fragment, hi only, duplicated across both K halves
__device__ __forceinline__ bf16x8_t build_u(float u0, float u1, float u2, float u3) {
    unsigned short h0 = bf16c(u0), h1 = bf16c(u1),
                   h2 = bf16c(u2), h3 = bf16c(u3);
    bf16x8_t B;
    B[0] = (short)h0; B[1] = (short)h1; B[2] = (short)h2; B[3] = (short)h3;
    B[4] = (short)h0; B[5] = (short)h1; B[6] = (short)h2; B[7] = (short)h3;
    return B;
}

__device__ __forceinline__ f32x4_t mm(bf16x8_t a, bf16x8_t b, f32x4_t c) {
    return __builtin_amdgcn_mfma_f32_16x16x32_bf16(a, b, c, 0, 0, 0);
}

__global__ __launch_bounds__(256)
__attribute__((amdgpu_waves_per_eu(3, 8)))
void gru_d_mfma(
    const float* __restrict__ h,
    const float* __restrict__ X,
    const float* __restrict__ M,
    const float* __restrict__ gam,
    const float* __restrict__ W_r, const float* __restrict__ W_z, const float* __restrict__ W_h,
    const float* __restrict__ U_r, const float* __restrict__ U_z, const float* __restrict__ U_h,
    const float* __restrict__ V_r, const float* __restrict__ V_z, const float* __restrict__ V_h,
    const float* __restrict__ b_r, const float* __restrict__ b_z, const float* __restrict__ b_h,
    float* __restrict__ out)
{
    __shared__ __align__(16) float shh[2][16 * SW];

    const int t  = threadIdx.x;
    const int w  = t >> 6;              // wave in block
    const int l  = t & 63;              // lane
    const int bi = l & 15;              // batch row within tile (phase 2)
    const int dA = (l >> 4) * 4;        // d-slot / out-col base (phase 2)
    const int r0 = 4 * w;               // staging rows for this wave

    const int i0  = blockIdx.x * 16;    // block's feature range (fixed)
    const int iw0 = i0 + w * 4;         // this wave's first i

    // ---- prologue: stage tile 0 into buffer 0 ----
    {
        const size_t b0p = (size_t)blockIdx.y * 16;
#define STAGE0(rr)                                                            \
        {                                                                     \
            const size_t gb = (b0p + r0 + (rr)) * ROWL + i0 * 16;             \
            float4 hv = *reinterpret_cast<const float4*>(h   + gb + 4 * l);   \
            float4 gv = *reinterpret_cast<const float4*>(gam + gb + 4 * l);   \
            float4 p;                                                         \
            p.x = hv.x * gv.x; p.y = hv.y * gv.y;                             \
            p.z = hv.z * gv.z; p.w = hv.w * gv.w;                             \
            *reinterpret_cast<float4*>(&shh[0][(r0 + (rr)) * SW + 4 * l]) = p;\
        }
        STAGE0(0) STAGE0(1) STAGE0(2) STAGE0(3)
#undef STAGE0
    }

    int cur = 0;
    #pragma unroll 1
    for (int k = 0; k < NTK; ++k) {
        __syncthreads();                      // buf[cur] staged for all waves
        const int b0 = (blockIdx.y + k * YB) * 16;
        float* sb  = shh[cur];
        float* sbn = shh[cur ^ 1];

        // ---- T14 issue-early: next tile's loads into named regs ----
        float4 lh0, lh1, lh2, lh3, lg0, lg1, lg2, lg3;
        if (k < NTK - 1) {
            const size_t nb0 = (size_t)(blockIdx.y + (k + 1) * YB) * 16;
            const size_t g0 = (nb0 + r0 + 0) * ROWL + i0 * 16;
            const size_t g1 = (nb0 + r0 + 1) * ROWL + i0 * 16;
            const size_t g2 = (nb0 + r0 + 2) * ROWL + i0 * 16;
            const size_t g3 = (nb0 + r0 + 3) * ROWL + i0 * 16;
            lh0 = *reinterpret_cast<const float4*>(h   + g0 + 4 * l);
            lh1 = *reinterpret_cast<const float4*>(h   + g1 + 4 * l);
            lh2 = *reinterpret_cast<const float4*>(h   + g2 + 4 * l);
            lh3 = *reinterpret_cast<const float4*>(h   + g3 + 4 * l);
            lg0 = *reinterpret_cast<const float4*>(gam + g0 + 4 * l);
            lg1 = *reinterpret_cast<const float4*>(gam + g1 + 4 * l);
            lg2 = *reinterpret_cast<const float4*>(gam + g2 + 4 * l);
            lg3 = *reinterpret_cast<const float4*>(gam + g3 + 4 * l);
        }

        // ================= Phase 2: lane-local MFMA over 4 i's =============
        const size_t xrow = (size_t)(b0 + bi) * I_TOT;

        float4 phh = *reinterpret_cast<const float4*>(&sb[bi * SW + (w * 4) * 16 + dA]);
        float px = X[xrow + iw0];
        float pm = M[xrow + iw0];
        const float* Urp = U_r + iw0 * 256 + bi;
        const float* Uzp = U_z + iw0 * 256 + bi;
        const float* Uhp = U_h + iw0 * 256 + bi;
        float pur0 = Urp[(dA+0)*16], pur1 = Urp[(dA+1)*16],
              pur2 = Urp[(dA+2)*16], pur3 = Urp[(dA+3)*16];
        float puz0 = Uzp[(dA+0)*16], puz1 = Uzp[(dA+1)*16],
              puz2 = Uzp[(dA+2)*16], puz3 = Uzp[(dA+3)*16];
        float puh0 = Uhp[(dA+0)*16], puh1 = Uhp[(dA+1)*16],
              puh2 = Uhp[(dA+2)*16], puh3 = Uhp[(dA+3)*16];

        #pragma unroll
        for (int it = 0; it < 4; ++it) {
            const int i = iw0 + it;

            const float4 wr4 = *reinterpret_cast<const float4*>(W_r + i*16 + dA);
            const float4 wz4 = *reinterpret_cast<const float4*>(W_z + i*16 + dA);
            const float4 wh4 = *reinterpret_cast<const float4*>(W_h + i*16 + dA);
            const float4 vr4 = *reinterpret_cast<const float4*>(V_r + i*16 + dA);
            const float4 vz4 = *reinterpret_cast<const float4*>(V_z + i*16 + dA);
            const float4 vh4 = *reinterpret_cast<const float4*>(V_h + i*16 + dA);
            const float4 br4 = *reinterpret_cast<const float4*>(b_r + i*16 + dA);
            const float4 bz4 = *reinterpret_cast<const float4*>(b_z + i*16 + dA);
            const float4 bh4 = *reinterpret_cast<const float4*>(b_h + i*16 + dA);

            bf16x8_t BUr = build_u(pur0, pur1, pur2, pur3);
            bf16x8_t BUz = build_u(puz0, puz1, puz2, puz3);
            bf16x8_t BUh = build_u(puh0, puh1, puh2, puh3);

            float hh0 = phh.x, hh1 = phh.y, hh2 = phh.z, hh3 = phh.w;
            bf16x8_t Ahh = build_a(hh0, hh1, hh2, hh3);

            float4 nhh; float nx, nm;
            float nur0, nur1, nur2, nur3, nuz0, nuz1, nuz2, nuz3,
                  nuh0, nuh1, nuh2, nuh3;
            if (it < 3) {
                const int ipf = i + 1;
                nhh = *reinterpret_cast<const float4*>(
                    &sb[bi * SW + (w * 4 + it + 1) * 16 + dA]);
                nx = X[xrow + ipf];
                nm = M[xrow + ipf];
                const float* nUr = U_r + ipf * 256 + bi;
                const float* nUz = U_z + ipf * 256 + bi;
                const float* nUh = U_h + ipf * 256 + bi;
                nur0 = nUr[(dA+0)*16]; nur1 = nUr[(dA+1)*16];
                nur2 = nUr[(dA+2)*16]; nur3 = nUr[(dA+3)*16];
                nuz0 = nUz[(dA+0)*16]; nuz1 = nUz[(dA+1)*16];
                nuz2 = nUz[(dA+2)*16]; nuz3 = nUz[(dA+3)*16];
                nuh0 = nUh[(dA+0)*16]; nuh1 = nUh[(dA+1)*16];
                nuh2 = nUh[(dA+2)*16]; nuh3 = nUh[(dA+3)*16];
            }

            f32x4_t initR, initZ, initH;
            initR[0] = fmaf(px, wr4.x, fmaf(pm, vr4.x, br4.x));
            initR[1] = fmaf(px, wr4.y, fmaf(pm, vr4.y, br4.y));
            initR[2] = fmaf(px, wr4.z, fmaf(pm, vr4.z, br4.z));
            initR[3] = fmaf(px, wr4.w, fmaf(pm, vr4.w, br4.w));
            initZ[0] = fmaf(px, wz4.x, fmaf(pm, vz4.x, bz4.x));
            initZ[1] = fmaf(px, wz4.y, fmaf(pm, vz4.y, bz4.y));
            initZ[2] = fmaf(px, wz4.z, fmaf(pm, vz4.z, bz4.z));
            initZ[3] = fmaf(px, wz4.w, fmaf(pm, vz4.w, bz4.w));
            f32x4_t accR = mm(BUr, Ahh, initR);
            f32x4_t accZ = mm(BUz, Ahh, initZ);

            float rh0 = fast_sigmoid(accR[0]) * hh0;
            float rh1 = fast_sigmoid(accR[1]) * hh1;
            float rh2 = fast_sigmoid(accR[2]) * hh2;
            float rh3 = fast_sigmoid(accR[3]) * hh3;
            bf16x8_t Arh = build_a(rh0, rh1, rh2, rh3);

            initH[0] = fmaf(px, wh4.x, fmaf(pm, vh4.x, bh4.x));
            initH[1] = fmaf(px, wh4.y, fmaf(pm, vh4.y, bh4.y));
            initH[2] = fmaf(px, wh4.z, fmaf(pm, vh4.z, bh4.z));
            initH[3] = fmaf(px, wh4.w, fmaf(pm, vh4.w, bh4.w));
            f32x4_t accH = mm(BUh, Arh, initH);

            float4 o;
            {
                float z0 = fast_sigmoid(accZ[0]); float t0 = fast_tanh(accH[0]);
                o.x = fmaf(z0, hh0 - t0, t0);
                float z1 = fast_sigmoid(accZ[1]); float t1 = fast_tanh(accH[1]);
                o.y = fmaf(z1, hh1 - t1, t1);
                float z2 = fast_sigmoid(accZ[2]); float t2 = fast_tanh(accH[2]);
                o.z = fmaf(z2, hh2 - t2, t2);
                float z3 = fast_sigmoid(accZ[3]); float t3 = fast_tanh(accH[3]);
                o.w = fmaf(z3, hh3 - t3, t3);
            }
            *reinterpret_cast<float4*>(&sb[bi * SW + (w * 4 + it) * 16 + dA]) = o;

            if (it < 3) {
                phh = nhh; px = nx; pm = nm;
                pur0 = nur0; pur1 = nur1; pur2 = nur2; pur3 = nur3;
                puz0 = nuz0; puz1 = nuz1; puz2 = nuz2; puz3 = nuz3;
                puh0 = nuh0; puh1 = nuh1; puh2 = nuh2; puh3 = nuh3;
            }
        }

        // ---- T14 write-late: stage next tile into the other buffer ----
        if (k < NTK - 1) {
            float4 p;
            p.x = lh0.x * lg0.x; p.y = lh0.y * lg0.y;
            p.z = lh0.z * lg0.z; p.w = lh0.w * lg0.w;
            *reinterpret_cast<float4*>(&sbn[(r0 + 0) * SW + 4 * l]) = p;
            p.x = lh1.x * lg1.x; p.y = lh1.y * lg1.y;
            p.z = lh1.z * lg1.z; p.w = lh1.w * lg1.w;
            *reinterpret_cast<float4*>(&sbn[(r0 + 1) * SW + 4 * l]) = p;
            p.x = lh2.x * lg2.x; p.y = lh2.y * lg2.y;
            p.z = lh2.z * lg2.z; p.w = lh2.w * lg2.w;
            *reinterpret_cast<float4*>(&sbn[(r0 + 2) * SW + 4 * l]) = p;
            p.x = lh3.x * lg3.x; p.y = lh3.y * lg3.y;
            p.z = lh3.z * lg3.z; p.w = lh3.w * lg3.w;
            *reinterpret_cast<float4*>(&sbn[(r0 + 3) * SW + 4 * l]) = p;
        }
        __syncthreads();                      // out-data in sb; sbn staged

        // ---- Phase 3: contiguous unstage sb -> out ----
        {
#define UNSTAGE(rr)                                                           \
            {                                                                 \
                const size_t gb = (size_t)(b0 + r0 + (rr)) * ROWL + i0 * 16;  \
                float4 v = *reinterpret_cast<const float4*>(                  \
                    &sb[(r0 + (rr)) * SW + 4 * l]);                           \
                *reinterpret_cast<float4*>(out + gb + 4 * l) = v;             \
            }
            UNSTAGE(0) UNSTAGE(1) UNSTAGE(2) UNSTAGE(3)
#undef UNSTAGE
        }

        cur ^= 1;
    }
}

extern "C" void kernel_launch(void* const* d_in, const int* in_sizes, int n_in,
                              void* d_out, int out_size, void* d_ws, size_t ws_size,
                              hipStream_t stream) {
    const float* h       = (const float*)d_in[0];
    const float* X       = (const float*)d_in[1];
    const float* M       = (const float*)d_in[2];
    const float* gamma_h = (const float*)d_in[3];
    const float* W_r     = (const float*)d_in[4];
    const float* W_z     = (const float*)d_in[5];
    const float* W_h     = (const float*)d_in[6];
    const float* U_r     = (const float*)d_in[7];
    const float* U_z     = (const float*)d_in[8];
    const float* U_h     = (const float*)d_in[9];
    const float* V_r     = (const float*)d_in[10];
    const float* V_z     = (const float*)d_in[11];
    const float* V_h     = (const float*)d_in[12];
    const float* b_r     = (const float*)d_in[13];
    const float* b_z     = (const float*)d_in[14];
    const float* b_h     = (const float*)d_in[15];
    float* out = (float*)d_out;

    dim3 grid(I_TOT / 16, YB);   // (8, 128) = 1024 blocks x 8 tiles each
    dim3 block(256);
    gru_d_mfma<<<grid, block, 0, stream>>>(h, X, M, gamma_h,
                                           W_r, W_z, W_h,
                                           U_r, U_z, U_h,
                                           V_r, V_z, V_h,
                                           b_r, b_z, b_h,
                                           out);
}

// Round 18
// 118.980 us; speedup vs baseline: 2.6389x; 2.6389x over previous
//
#include <hip/hip_runtime.h>
#include <hip/hip_bf16.h>

// GRU-D cell: B=16384, I=128, D=16 -- R18: R16's fully-staged structure +
// R17's two mechanisms re-implemented with ZERO register cost:
//  (1) param warmth: block owns a 16-i range, loops 8 b-tiles -> U/W/V/b
//      gathers are L1-warm after tile 0 (R17 proved the concept, died on
//      spills from register-held staging).
//  (2) async staging via __builtin_amdgcn_global_load_lds: DMA tile k+1's
//      h/gamma rows into the alternate LDS buffer (no VGPRs, no wave
//      stall), compute tile k, and let the barrier's vmcnt drain land the
//      DMA after ~1400cy of compute has covered HBM latency.
// Each row segment is exactly 64 lanes x 16 B = 1 KB contiguous: the DMA's
// wave-uniform-LDS-base + lane*16 constraint is satisfied per-instruction;
// the +4-word row pad lives BETWEEN instructions (m104-safe).
// LDS 4 x 16.6 KB = 66 KB -> 2 blocks/CU (occupancy shown non-binding, R15).

typedef float  f32x4_t  __attribute__((ext_vector_type(4)));
typedef short  bf16x8_t __attribute__((ext_vector_type(8)));

constexpr int I_TOT = 128;
constexpr int ROWL  = 2048;   // floats per batch row (I*D)
constexpr int SW    = 260;    // LDS row stride in words (256 + 4 pad)
constexpr int NTK   = 8;      // b-tiles per block
constexpr int YB    = 128;    // grid.y

#define GLD16(gsrc, ldst)                                                     \
    __builtin_amdgcn_global_load_lds(                                         \
        (const __attribute__((address_space(1))) void*)(gsrc),                \
        (__attribute__((address_space(3))) void*)(ldst), 16, 0, 0)

__device__ __forceinline__ unsigned short bf16c(float x) {
    union { __hip_bfloat16 b; unsigned short u; } cv;
    cv.b = __float2bfloat16(x);
    return cv.u;
}
__device__ __forceinline__ float bf16_to_f(unsigned short b) {
    union { float f; unsigned u; } c; c.u = ((unsigned)b) << 16;
    return c.f;
}
__device__ __forceinline__ float fast_sigmoid(float x) {
    float e = __expf(-x);
    return __builtin_amdgcn_rcpf(1.0f + e);
}
__device__ __forceinline__ float fast_tanh(float x) {
    x = fminf(fmaxf(x, -10.0f), 10.0f);
    float e = __expf(-2.0f * x);
    return (1.0f - e) * __builtin_amdgcn_rcpf(1.0f + e);
}

// compensated A fragment: [hi(a0..a3) | lo(a0..a3)]
__device__ __forceinline__ bf16x8_t build_a(float a0, float a1, float a2, float a3) {
    unsigned short h0 = bf16c(a0), h1 = bf16c(a1),
                   h2 = bf16c(a2), h3 = bf16c(a3);
    unsigned short l0 = bf16c(a0 - bf16_to_f(h0));
    unsigned short l1 = bf16c(a1 - bf16_to_f(h1));
    unsigned short l2 = bf16c(a2 - bf16_to_f(h2));
    unsigned short l3 = bf16c(a3 - bf16_to_f(h3));
    bf16x8_t A;
    A[0] = (short)h0; A[1] = (short)h1; A[2] = (short)h2; A[3] = (short)h3;
    A[4] = (short)l0; A[5] = (short)l1; A[6] = (short)l2; A[7] = (short)l3;
    return A;
}

// U fragment, hi only, duplicated across both K halves
__device__ __forceinline__ bf16x8_t build_u(float u0, float u1, float u2, float u3) {
    unsigned short h0 = bf16c(u0), h1 = bf16c(u1),
                   h2 = bf16c(u2), h3 = bf16c(u3);
    bf16x8_t B;
    B[0] = (short)h0; B[1] = (short)h1; B[2] = (short)h2; B[3] = (short)h3;
    B[4] = (short)h0; B[5] = (short)h1; B[6] = (short)h2; B[7] = (short)h3;
    return B;
}

__device__ __forceinline__ f32x4_t mm(bf16x8_t a, bf16x8_t b, f32x4_t c) {
    return __builtin_amdgcn_mfma_f32_16x16x32_bf16(a, b, c, 0, 0, 0);
}

__global__ __launch_bounds__(256)
void gru_d_mfma(
    const float* __restrict__ h,
    const float* __restrict__ X,
    const float* __restrict__ M,
    const float* __restrict__ gam,
    const float* __restrict__ W_r, const float* __restrict__ W_z, const float* __restrict__ W_h,
    const float* __restrict__ U_r, const float* __restrict__ U_z, const float* __restrict__ U_h,
    const float* __restrict__ V_r, const float* __restrict__ V_z, const float* __restrict__ V_h,
    const float* __restrict__ b_r, const float* __restrict__ b_z, const float* __restrict__ b_h,
    float* __restrict__ out)
{
    __shared__ __align__(16) float sh[2][16 * SW];   // h tiles (later: out)
    __shared__ __align__(16) float sg[2][16 * SW];   // gamma tiles

    const int t  = threadIdx.x;
    const int w  = t >> 6;              // wave in block
    const int l  = t & 63;              // lane
    const int bi = l & 15;              // batch row within tile (phase 2)
    const int dA = (l >> 4) * 4;        // d-slot / out-col base (phase 2)
    const int r0 = 4 * w;               // staging rows for this wave

    const int i0  = blockIdx.x * 16;    // block's feature range (fixed)
    const int iw0 = i0 + w * 4;         // this wave's first i

    // ---- prologue: DMA tile 0 into buffer 0 ----
    {
        const size_t b0p = (size_t)blockIdx.y * 16;
        #pragma unroll
        for (int rr = 0; rr < 4; ++rr) {
            const size_t gb = (b0p + r0 + rr) * ROWL + i0 * 16;
            GLD16(h   + gb + 4 * l, &sh[0][(r0 + rr) * SW]);
            GLD16(gam + gb + 4 * l, &sg[0][(r0 + rr) * SW]);
        }
    }

    int cur = 0;
    #pragma unroll 1
    for (int k = 0; k < NTK; ++k) {
        __syncthreads();   // drains vmcnt: buf[cur] DMA complete; also
                           // orders last iter's unstage before new DMA
        const int b0 = (blockIdx.y + k * YB) * 16;
        float* sbh = sh[cur];
        float* sbg = sg[cur];

        // ---- async DMA of tile k+1 into the alternate buffers ----
        if (k < NTK - 1) {
            const size_t nb0 = (size_t)(blockIdx.y + (k + 1) * YB) * 16;
            #pragma unroll
            for (int rr = 0; rr < 4; ++rr) {
                const size_t gb = (nb0 + r0 + rr) * ROWL + i0 * 16;
                GLD16(h   + gb + 4 * l, &sh[cur ^ 1][(r0 + rr) * SW]);
                GLD16(gam + gb + 4 * l, &sg[cur ^ 1][(r0 + rr) * SW]);
            }
        }

        // ================= Phase 2: lane-local MFMA over 4 i's =============
        const size_t xrow = (size_t)(b0 + bi) * I_TOT;

        float4 phv = *reinterpret_cast<const float4*>(&sbh[bi * SW + (w * 4) * 16 + dA]);
        float4 pgv = *reinterpret_cast<const float4*>(&sbg[bi * SW + (w * 4) * 16 + dA]);
        float px = X[xrow + iw0];
        float pm = M[xrow + iw0];
        const float* Urp = U_r + iw0 * 256 + bi;
        const float* Uzp = U_z + iw0 * 256 + bi;
        const float* Uhp = U_h + iw0 * 256 + bi;
        float pur0 = Urp[(dA+0)*16], pur1 = Urp[(dA+1)*16],
              pur2 = Urp[(dA+2)*16], pur3 = Urp[(dA+3)*16];
        float puz0 = Uzp[(dA+0)*16], puz1 = Uzp[(dA+1)*16],
              puz2 = Uzp[(dA+2)*16], puz3 = Uzp[(dA+3)*16];
        float puh0 = Uhp[(dA+0)*16], puh1 = Uhp[(dA+1)*16],
              puh2 = Uhp[(dA+2)*16], puh3 = Uhp[(dA+3)*16];

        #pragma unroll
        for (int it = 0; it < 4; ++it) {
            const int i = iw0 + it;

            const float4 wr4 = *reinterpret_cast<const float4*>(W_r + i*16 + dA);
            const float4 wz4 = *reinterpret_cast<const float4*>(W_z + i*16 + dA);
            const float4 wh4 = *reinterpret_cast<const float4*>(W_h + i*16 + dA);
            const float4 vr4 = *reinterpret_cast<const float4*>(V_r + i*16 + dA);
            const float4 vz4 = *reinterpret_cast<const float4*>(V_z + i*16 + dA);
            const float4 vh4 = *reinterpret_cast<const float4*>(V_h + i*16 + dA);
            const float4 br4 = *reinterpret_cast<const float4*>(b_r + i*16 + dA);
            const float4 bz4 = *reinterpret_cast<const float4*>(b_z + i*16 + dA);
            const float4 bh4 = *reinterpret_cast<const float4*>(b_h + i*16 + dA);

            bf16x8_t BUr = build_u(pur0, pur1, pur2, pur3);
            bf16x8_t BUz = build_u(puz0, puz1, puz2, puz3);
            bf16x8_t BUh = build_u(puh0, puh1, puh2, puh3);

            const float hh0 = phv.x * pgv.x, hh1 = phv.y * pgv.y,
                        hh2 = phv.z * pgv.z, hh3 = phv.w * pgv.w;
            bf16x8_t Ahh = build_a(hh0, hh1, hh2, hh3);

            float4 nhv, ngv; float nx, nm;
            float nur0, nur1, nur2, nur3, nuz0, nuz1, nuz2, nuz3,
                  nuh0, nuh1, nuh2, nuh3;
            if (it < 3) {
                const int ipf = i + 1;
                nhv = *reinterpret_cast<const float4*>(
                    &sbh[bi * SW + (w * 4 + it + 1) * 16 + dA]);
                ngv = *reinterpret_cast<const float4*>(
                    &sbg[bi * SW + (w * 4 + it + 1) * 16 + dA]);
                nx = X[xrow + ipf];
                nm = M[xrow + ipf];
                const float* nUr = U_r + ipf * 256 + bi;
                const float* nUz = U_z + ipf * 256 + bi;
                const float* nUh = U_h + ipf * 256 + bi;
                nur0 = nUr[(dA+0)*16]; nur1 = nUr[(dA+1)*16];
                nur2 = nUr[(dA+2)*16]; nur3 = nUr[(dA+3)*16];
                nuz0 = nUz[(dA+0)*16]; nuz1 = nUz[(dA+1)*16];
                nuz2 = nUz[(dA+2)*16]; nuz3 = nUz[(dA+3)*16];
                nuh0 = nUh[(dA+0)*16]; nuh1 = nUh[(dA+1)*16];
                nuh2 = nUh[(dA+2)*16]; nuh3 = nUh[(dA+3)*16];
            }

            f32x4_t initR, initZ, initH;
            initR[0] = fmaf(px, wr4.x, fmaf(pm, vr4.x, br4.x));
            initR[1] = fmaf(px, wr4.y, fmaf(pm, vr4.y, br4.y));
            initR[2] = fmaf(px, wr4.z, fmaf(pm, vr4.z, br4.z));
            initR[3] = fmaf(px, wr4.w, fmaf(pm, vr4.w, br4.w));
            initZ[0] = fmaf(px, wz4.x, fmaf(pm, vz4.x, bz4.x));
            initZ[1] = fmaf(px, wz4.y, fmaf(pm, vz4.y, bz4.y));
            initZ[2] = fmaf(px, wz4.z, fmaf(pm, vz4.z, bz4.z));
            initZ[3] = fmaf(px, wz4.w, fmaf(pm, vz4.w, bz4.w));
            f32x4_t accR = mm(BUr, Ahh, initR);
            f32x4_t accZ = mm(BUz, Ahh, initZ);

            float rh0 = fast_sigmoid(accR[0]) * hh0;
            float rh1 = fast_sigmoid(accR[1]) * hh1;
            float rh2 = fast_sigmoid(accR[2]) * hh2;
            float rh3 = fast_sigmoid(accR[3]) * hh3;
            bf16x8_t Arh = build_a(rh0, rh1, rh2, rh3);

            initH[0] = fmaf(px, wh4.x, fmaf(pm, vh4.x, bh4.x));
            initH[1] = fmaf(px, wh4.y, fmaf(pm, vh4.y, bh4.y));
            initH[2] = fmaf(px, wh4.z, fmaf(pm, vh4.z, bh4.z));
            initH[3] = fmaf(px, wh4.w, fmaf(pm, vh4.w, bh4.w));
            f32x4_t accH = mm(BUh, Arh, initH);

            float4 o;
            {
                float z0 = fast_sigmoid(accZ[0]); float t0 = fast_tanh(accH[0]);
                o.x = fmaf(z0, hh0 - t0, t0);
                float z1 = fast_sigmoid(accZ[1]); float t1 = fast_tanh(accH[1]);
                o.y = fmaf(z1, hh1 - t1, t1);
                float z2 = fast_sigmoid(accZ[2]); float t2 = fast_tanh(accH[2]);
                o.z = fmaf(z2, hh2 - t2, t2);
                float z3 = fast_sigmoid(accZ[3]); float t3 = fast_tanh(accH[3]);
                o.w = fmaf(z3, hh3 - t3, t3);
            }
            // in-place: this lane's slot, read (prefetch) before write
            *reinterpret_cast<float4*>(&sbh[bi * SW + (w * 4 + it) * 16 + dA]) = o;

            if (it < 3) {
                phv = nhv; pgv = ngv; px = nx; pm = nm;
                pur0 = nur0; pur1 = nur1; pur2 = nur2; pur3 = nur3;
                puz0 = nuz0; puz1 = nuz1; puz2 = nuz2; puz3 = nuz3;
                puh0 = nuh0; puh1 = nuh1; puh2 = nuh2; puh3 = nuh3;
            }
        }
        __syncthreads();   // out-data complete in sbh; k+1 DMA also drained

        // ---- Phase 3: contiguous unstage sbh -> out ----
        #pragma unroll
        for (int rr = 0; rr < 4; ++rr) {
            const size_t gb = (size_t)(b0 + r0 + rr) * ROWL + i0 * 16;
            float4 v = *reinterpret_cast<const float4*>(&sbh[(r0 + rr) * SW + 4 * l]);
            *reinterpret_cast<float4*>(out + gb + 4 * l) = v;
        }

        cur ^= 1;
    }
}

extern "C" void kernel_launch(void* const* d_in, const int* in_sizes, int n_in,
                              void* d_out, int out_size, void* d_ws, size_t ws_size,
                              hipStream_t stream) {
    const float* h       = (const float*)d_in[0];
    const float* X       = (const float*)d_in[1];
    const float* M       = (const float*)d_in[2];
    const float* gamma_h = (const float*)d_in[3];
    const float* W_r     = (const float*)d_in[4];
    const float* W_z     = (const float*)d_in[5];
    const float* W_h     = (const float*)d_in[6];
    const float* U_r     = (const float*)d_in[7];
    const float* U_z     = (const float*)d_in[8];
    const float* U_h     = (const float*)d_in[9];
    const float* V_r     = (const float*)d_in[10];
    const float* V_z     = (const float*)d_in[11];
    const float* V_h     = (const float*)d_in[12];
    const float* b_r     = (const float*)d_in[13];
    const float* b_z     = (const float*)d_in[14];
    const float* b_h     = (const float*)d_in[15];
    float* out = (float*)d_out;

    dim3 grid(I_TOT / 16, YB);   // (8, 128) = 1024 blocks x 8 tiles each
    dim3 block(256);
    gru_d_mfma<<<grid, block, 0, stream>>>(h, X, M, gamma_h,
                                           W_r, W_z, W_h,
                                           U_r, U_z, U_h,
                                           V_r, V_z, V_h,
                                           b_r, b_z, b_h,
                                           out);
}